// Round 7
// baseline (563.913 us; speedup 1.0000x reference)
//
#include <hip/hip_runtime.h>
#include <math.h>

typedef __bf16 bf16;
typedef __bf16 bf16x8 __attribute__((ext_vector_type(8)));
typedef __bf16 bf16x4 __attribute__((ext_vector_type(4)));
typedef float f32x4 __attribute__((ext_vector_type(4)));

#define B_ROWS 32768
#define ROWS 48           // rows per block (3x16); grid 683, tail block has 32 valid
#define PSZ 8192          // panel: 256 n-rows x 32 k, bf16 elems (16 KB)
#define PBYTES 16384

// panel-index bases in ws (panel-major, n-major within panel, UNSWIZZLED)
#define PB_PW0   0    // 4 panels  (K=128)
#define PB_PW1   4    // 8
#define PB_PW2   12   // 16
#define PB_RW1   28   // 6*16
#define PB_LPW1  124  // 3*8
#define PB_LPW2  148  // 3*8
#define PB_FAW1  172  // 24
#define PB_FAW2  196  // 8   (total 204 panels = 3.34 MB)

// Panel image: dst[n*32 + k'] = src[(kp*32 + k')*256 + n]  (fp32->bf16).
__global__ void wprep_kernel(const float* __restrict__ pW0, const float* __restrict__ pW1,
                             const float* __restrict__ pW2, const float* __restrict__ rW1,
                             const float* __restrict__ lpW1, const float* __restrict__ lpW2,
                             const float* __restrict__ faW1, const float* __restrict__ faW2,
                             bf16* __restrict__ ws) {
  int p = blockIdx.x;
  const float* src; int kp;
  if (p < 4)        { src = pW0;  kp = p; }
  else if (p < 12)  { src = pW1;  kp = p - 4; }
  else if (p < 28)  { src = pW2;  kp = p - 12; }
  else if (p < 124) { int q = p - 28;  src = rW1  + (size_t)(q >> 4) * 512 * 256; kp = q & 15; }
  else if (p < 148) { int q = p - 124; src = lpW1 + (size_t)(q >> 3) * 256 * 256; kp = q & 7; }
  else if (p < 172) { int q = p - 148; src = lpW2 + (size_t)(q >> 3) * 256 * 256; kp = q & 7; }
  else if (p < 196) { src = faW1; kp = p - 172; }
  else              { src = faW2; kp = p - 196; }
  bf16* dst = ws + (size_t)p * PSZ;
  int n = threadIdx.x;  // 256 threads, one n-row each
#pragma unroll
  for (int kb = 0; kb < 32; kb += 8) {
    bf16x8 v;
#pragma unroll
    for (int j = 0; j < 8; j++)
      v[j] = (bf16)src[(size_t)(kp * 32 + kb + j) * 256 + n];  // coalesced over n
    *(bf16x8*)(dst + n * 32 + kb) = v;
  }
}

#define FENCE asm volatile("" ::: "memory")
#define BAR()  do { FENCE; __builtin_amdgcn_s_barrier(); FENCE; } while (0)
#define BARP() do { asm volatile("s_waitcnt lgkmcnt(0)" ::: "memory"); \
                    __builtin_amdgcn_s_barrier(); FENCE; } while (0)
// Dataflow-tied counted waits (NO sched_barrier wall): the wait redefines the
// B slot it guards, so consuming MFMAs cannot hoist above it (rule #18), while
// the scheduler stays free to move independent work across the wait.
#define VWB2(N, B) asm volatile("s_waitcnt vmcnt(" #N ")" \
                                : "+v"(B[0]), "+v"(B[1]) :: "memory")
#define VWB4(N, B) asm volatile("s_waitcnt vmcnt(" #N ")" \
                                : "+v"(B[0]), "+v"(B[1]), "+v"(B[2]), "+v"(B[3]) :: "memory")

// 2 x global_load_dwordx4 of one 32-col B sub-panel into pinned registers.
__device__ __forceinline__ void ld2(bf16x8& d0, bf16x8& d1, const void* addr) {
  asm volatile("global_load_dwordx4 %0, %2, off\n\t"
               "global_load_dwordx4 %1, %2, off offset:1024"
               : "=&v"(d0), "=&v"(d1)
               : "v"(addr));
}
// 4 x global_load_dwordx4 of one 64-col B sub-panel into pinned registers.
__device__ __forceinline__ void ld4(bf16x8& d0, bf16x8& d1, bf16x8& d2, bf16x8& d3,
                                    const void* addr) {
  asm volatile("global_load_dwordx4 %0, %4, off\n\t"
               "global_load_dwordx4 %1, %4, off offset:1024\n\t"
               "global_load_dwordx4 %2, %4, off offset:2048\n\t"
               "global_load_dwordx4 %3, %4, off offset:3072"
               : "=&v"(d0), "=&v"(d1), "=&v"(d2), "=&v"(d3)
               : "v"(addr));
}

// 48-row blocks (grid 683), 512 threads = 8 waves. LDS ~78 KB -> TWO blocks
// co-reside per CU = 4 waves/SIMD, the first real TLP increase of the
// session (ledger: every prior config was 2 waves/SIMD; R6 falsified the
// load-latency theory -- the ~60% idle is dual-wave stall on barriers/
// epilogue chains, which only TLP can hide). Pipelines revert to the
// R0-proven shallow depths (dist-2 routing vmcnt(4), dist-4 narrow
// vmcnt(6)): phase re-issue distance ~620cyc already covers ~300cyc L2
// latency. acc[12] (3 row-tiles x 4 col-tiles). waves_per_eu(2,4): min=2
// keeps the only spill-free allocation regime seen (R0/R4/R5/R6 all
// 108-128 VGPR); max=4 lifts the residency cap that blocked R4.
// Tail block: clamped x-loads, guarded global stores; LDS rows 32..47
// compute garbage that never escapes (per-row ops, guarded stores).
__global__ void __launch_bounds__(512)
__attribute__((amdgpu_waves_per_eu(2, 4)))
fused_kernel(const float* __restrict__ xf, const float* __restrict__ xm,
                  const float* __restrict__ xc,
                  const float* __restrict__ pb0, const float* __restrict__ pb1v,
                  const float* __restrict__ pb2v,
                  const float* __restrict__ rb1, const float* __restrict__ rW2,
                  const float* __restrict__ rb2,
                  const float* __restrict__ lpb1, const float* __restrict__ lpb2,
                  const float* __restrict__ lng, const float* __restrict__ lnb,
                  const float* __restrict__ fab1, const float* __restrict__ fab2,
                  const float* __restrict__ fng, const float* __restrict__ fnb,
                  const bf16* __restrict__ ws, float* __restrict__ out) {
  __shared__ bf16 feats[3][ROWS][256];   // 72 KB
  __shared__ char scratch[3072];         // apan[48][32] bf16 UNION lnred[8][2][48] f32
  __shared__ float w_route[6][ROWS];     // 1152 B

  const int t = threadIdx.x;
  const int lane = t & 63;
  const int cg = t >> 6;               // wave id, 0..7
  const int lr = lane & 15;
  const int lk = lane >> 4;
  const int r0 = blockIdx.x * ROWS;

  char* featsB = (char*)&feats[0][0][0];
  char* apanB  = scratch;
  float (*lnred)[2][ROWS] = (float (*)[2][ROWS])scratch;  // [cg][sum/sq][row]

  f32x4 acc[12];  // routing: [rt*4+ct] rt<3,ct<4 ; narrow path: [rt*2+ct] ct<2
  auto zacc12 = [&]() {
#pragma unroll
    for (int i = 0; i < 12; i++) acc[i] = (f32x4){0.f, 0.f, 0.f, 0.f};
  };
  auto zacc6 = [&]() {
#pragma unroll
    for (int i = 0; i < 6; i++) acc[i] = (f32x4){0.f, 0.f, 0.f, 0.f};
  };

  auto mf = [&](bf16x8* Av, bf16x8* Bv) {   // 48x32 tile: 6 MFMA
    __builtin_amdgcn_s_setprio(1);
#pragma unroll
    for (int rt = 0; rt < 3; rt++)
#pragma unroll
      for (int ct = 0; ct < 2; ct++)
        acc[rt * 2 + ct] = __builtin_amdgcn_mfma_f32_16x16x32_bf16(Av[rt], Bv[ct], acc[rt * 2 + ct], 0, 0, 0);
    __builtin_amdgcn_s_setprio(0);
  };
  auto mfR = [&](bf16x8* Av, bf16x8* Bv) {  // 48x64 tile: 12 MFMA
    __builtin_amdgcn_s_setprio(1);
#pragma unroll
    for (int rt = 0; rt < 3; rt++)
#pragma unroll
      for (int ct = 0; ct < 4; ct++)
        acc[rt * 4 + ct] = __builtin_amdgcn_mfma_f32_16x16x32_bf16(Av[rt], Bv[ct], acc[rt * 4 + ct], 0, 0, 0);
    __builtin_amdgcn_s_setprio(0);
  };

  const int SRCa[6] = {0, 0, 1, 1, 2, 2};
  const int TGTa[6] = {1, 2, 0, 2, 0, 1};

  // Merged routing-pair GEMM (p0 even): 16 phases, wave tile 48x64,
  // B distance-2 pinned (8 loads in flight, dataflow-tied vmcnt(4)).
  auto gemmR = [&](int p0) {
    const int pp = p0 + (cg >> 2);
    const char* Wb = (const char*)(ws + (size_t)(PB_RW1 + pp * 16) * PSZ)
                     + (((cg & 3) * 64 + lr) * 64 + lk * 16);
    const int lS = SRCa[p0];
    const int lT = TGTa[pp];
    bf16x8 Ba[4], Bb[4], Aa[3], Ab[3];
    auto ldB = [&](int s, bf16x8* Bv) {
      ld4(Bv[0], Bv[1], Bv[2], Bv[3], Wb + (size_t)s * PBYTES);
    };
    auto readA = [&](int s, bf16x8* Av) {
      int lvl = (s < 8) ? lS : lT;
      int q = (s & 7) * 4;
#pragma unroll
      for (int rt = 0; rt < 3; rt++) {
        int r = rt * 16 + lr;
        Av[rt] = *(const bf16x8*)(featsB + ((lvl * ROWS + r) << 9) + (((q + lk) ^ (r & 7)) << 4));
      }
    };
    ldB(0, Ba); ldB(1, Bb);   // 8 loads in flight
    readA(0, Aa);
    int s = 0;
#pragma unroll 1
    for (; s < 14; s += 2) {
      readA(s + 1, Ab); VWB4(4, Ba); mfR(Aa, Ba); ldB(s + 2, Ba);
      readA(s + 2, Aa); VWB4(4, Bb); mfR(Ab, Bb); ldB(s + 3, Bb);
    }
    // tail: phases 14 (Aa,Ba), 15 (Ab,Bb)
    readA(15, Ab); VWB4(4, Ba); mfR(Aa, Ba);
    VWB4(0, Bb); mfR(Ab, Bb);
  };

  // Merged routing epilogue: gates for p0 (waves 0-3) and p0+1 (waves 4-7).
  auto routing_epi2 = [&](int p0) {
    const int pp = p0 + (cg >> 2);
    float part[3][4] = {{0}};
#pragma unroll
    for (int ct = 0; ct < 4; ct++) {
      int col = (cg & 3) * 64 + ct * 16 + lr;
      float b1 = rb1[pp * 256 + col];
      float w2 = rW2[pp * 256 + col];
#pragma unroll
      for (int rt = 0; rt < 3; rt++)
#pragma unroll
        for (int e = 0; e < 4; e++)
          part[rt][e] += fmaxf(acc[rt * 4 + ct][e] + b1, 0.f) * w2;
    }
#pragma unroll
    for (int m = 1; m < 16; m <<= 1)
#pragma unroll
      for (int rt = 0; rt < 3; rt++)
#pragma unroll
        for (int e = 0; e < 4; e++)
          part[rt][e] += __shfl_xor(part[rt][e], m, 64);
    if (lr == 0)
#pragma unroll
      for (int rt = 0; rt < 3; rt++)
#pragma unroll
        for (int e = 0; e < 4; e++)
          lnred[cg][0][rt * 16 + lk * 4 + e] = part[rt][e];
    BARP();
    if (t < 2 * ROWS) {
      int pi = t / ROWS, r = t % ROWS;
      float s = rb2[p0 + pi];
#pragma unroll
      for (int g = 0; g < 4; g++) s += lnred[pi * 4 + g][0][r];
      w_route[p0 + pi][r] = 1.f / (1.f + expf(-s));
    }
    BARP();
  };

  // Narrow GEMM (lp/fa): wave tile 48x32, B distance-4 pinned, vmcnt(6).
  auto gemm = [&](const bf16* W, int n, int l0, int l1, int l2) {
    const char* Wb = (const char*)W + ((cg * 32 + lr) * 64 + lk * 16);
    bf16x8 B0[2], B1[2], B2[2], B3[2], A0[3], A1[3];
    auto ldB = [&](int s, bf16x8* Bv) {
      ld2(Bv[0], Bv[1], Wb + (size_t)s * PBYTES);
    };
    auto readA = [&](int s, bf16x8* Av) {
      int lvl = (s >= 16) ? l2 : ((s >= 8) ? l1 : l0);
      int q = (s & 7) * 4;
#pragma unroll
      for (int rt = 0; rt < 3; rt++) {
        int r = rt * 16 + lr;
        Av[rt] = *(const bf16x8*)(featsB + ((lvl * ROWS + r) << 9) + (((q + lk) ^ (r & 7)) << 4));
      }
    };
    ldB(0, B0); ldB(1, B1); ldB(2, B2); ldB(3, B3);   // 8 loads in flight
    readA(0, A0);
    int s = 0;
#pragma unroll 1
    for (; s < n - 4; s += 4) {
      readA(s + 1, A1); VWB2(6, B0); mf(A0, B0); ldB(s + 4, B0);
      readA(s + 2, A0); VWB2(6, B1); mf(A1, B1); ldB(s + 5, B1);
      readA(s + 3, A1); VWB2(6, B2); mf(A0, B2); ldB(s + 6, B2);
      readA(s + 4, A0); VWB2(6, B3); mf(A1, B3); ldB(s + 7, B3);
    }
    readA(s + 1, A1); VWB2(6, B0); mf(A0, B0);
    readA(s + 2, A0); VWB2(4, B1); mf(A1, B1);
    readA(s + 3, A1); VWB2(2, B2); mf(A0, B2);
    VWB2(0, B3); mf(A1, B3);
  };

  // Projection GEMM: A = x (fp32 global) staged through apan; B direct.
  auto gemm_x = [&](const bf16* W, int n, const float* X, int Kx) {
    const char* Wb = (const char*)W + ((cg * 32 + lr) * 64 + lk * 16);
    int rr = t >> 3, c0 = (t & 7) * 4;
    int row = r0 + rr; if (row > B_ROWS - 1) row = B_ROWS - 1;  // tail clamp
#pragma unroll 1
    for (int s = 0; s < n; s++) {
      bf16x8 b[2];
#pragma unroll
      for (int ct = 0; ct < 2; ct++)
        b[ct] = *(const bf16x8*)(Wb + (size_t)s * PBYTES + ct * 1024);
      float4 xv = *(const float4*)(X + (size_t)row * Kx + s * 32 + c0);
      BAR();
      if (rr < ROWS) {
        bf16x4 v;
        v[0] = (bf16)xv.x; v[1] = (bf16)xv.y; v[2] = (bf16)xv.z; v[3] = (bf16)xv.w;
        int cb = c0 >> 3;
        *(bf16x4*)(apanB + (rr << 6) + ((cb ^ ((rr >> 1) & 3)) << 4) + (c0 & 7) * 2) = v;
      }
      BARP();
      bf16x8 a[3];
#pragma unroll
      for (int rt = 0; rt < 3; rt++) {
        int r = rt * 16 + lr;
        a[rt] = *(const bf16x8*)(apanB + (r << 6) + ((lk ^ ((r >> 1) & 3)) << 4));
      }
      mf(a, b);
    }
  };

  auto stF = [&](int lvl, int r, int c, float v) {
    *(bf16*)(featsB + ((lvl * ROWS + r) << 9) +
             ((((c >> 3) ^ (r & 7))) << 4) + (c & 7) * 2) = (bf16)v;
  };
  auto epi_bias_store = [&](const float* bias, int lvl, bool do_relu) {
    BAR();
#pragma unroll
    for (int ct = 0; ct < 2; ct++) {
      int col = cg * 32 + ct * 16 + lr;
      float bv = bias[col];
#pragma unroll
      for (int rt = 0; rt < 3; rt++)
#pragma unroll
        for (int e = 0; e < 4; e++) {
          float v = acc[rt * 2 + ct][e] + bv;
          if (do_relu) v = fmaxf(v, 0.f);
          stF(lvl, rt * 16 + lk * 4 + e, col, v);
        }
    }
    BARP();
  };
  auto ln_epi = [&](const float* bias, const float* gamma, const float* beta, int lvl) {
    float sum[3][4] = {{0}}, sq[3][4] = {{0}};
#pragma unroll
    for (int ct = 0; ct < 2; ct++) {
      int col = cg * 32 + ct * 16 + lr;
      float bv = bias[col];
#pragma unroll
      for (int rt = 0; rt < 3; rt++)
#pragma unroll
        for (int e = 0; e < 4; e++) {
          float v = acc[rt * 2 + ct][e] + bv;
          acc[rt * 2 + ct][e] = v;
          sum[rt][e] += v; sq[rt][e] += v * v;
        }
    }
#pragma unroll
    for (int m = 1; m < 16; m <<= 1)
#pragma unroll
      for (int rt = 0; rt < 3; rt++)
#pragma unroll
        for (int e = 0; e < 4; e++) {
          sum[rt][e] += __shfl_xor(sum[rt][e], m, 64);
          sq[rt][e]  += __shfl_xor(sq[rt][e], m, 64);
        }
    if (lr == 0)
#pragma unroll
      for (int rt = 0; rt < 3; rt++)
#pragma unroll
        for (int e = 0; e < 4; e++) {
          int r = rt * 16 + lk * 4 + e;
          lnred[cg][0][r] = sum[rt][e];
          lnred[cg][1][r] = sq[rt][e];
        }
    BARP();
    if (t < ROWS) {
      float su = 0.f, sz = 0.f;
#pragma unroll
      for (int g = 0; g < 8; g++) { su += lnred[g][0][t]; sz += lnred[g][1][t]; }
      float mu = su * (1.f / 256.f);
      float ms = sz * (1.f / 256.f);
      lnred[0][0][t] = mu;
      lnred[0][1][t] = rsqrtf(ms - mu * mu + 1e-5f);
    }
    BARP();
#pragma unroll
    for (int rt = 0; rt < 3; rt++)
#pragma unroll
      for (int e = 0; e < 4; e++) {
        int r = rt * 16 + lk * 4 + e;
        float mu = lnred[0][0][r];
        float rstd = lnred[0][1][r];
#pragma unroll
        for (int ct = 0; ct < 2; ct++) {
          int col = cg * 32 + ct * 16 + lr;
          float v = (acc[rt * 2 + ct][e] - mu) * rstd * gamma[col] + beta[col];
          if (lvl >= 0) stF(lvl, r, col, v);
          else if (r0 + r < B_ROWS) out[(size_t)(r0 + r) * 256 + col] = v;
        }
      }
    BARP();
  };

  // ---------------- schedule ----------------
  zacc6(); gemm_x(ws + PB_PW0 * PSZ, 4,  xf, 128); epi_bias_store(pb0, 0, false);
  zacc6(); gemm_x(ws + PB_PW1 * PSZ, 8,  xm, 256); epi_bias_store(pb1v, 1, false);
  zacc6(); gemm_x(ws + PB_PW2 * PSZ, 16, xc, 512); epi_bias_store(pb2v, 2, false);

  for (int it = 0; it < 3; it++) {
    for (int p0 = 0; p0 < 6; p0 += 2) {
      zacc12();
      gemmR(p0);
      routing_epi2(p0);
    }
    // upd = feats + segment_sum(w * src)  (in place, disjoint per thread)
    {
      int r = t >> 3, c0 = (t & 7) * 32;
      if (r < ROWS) {
        float w6[6];
#pragma unroll
        for (int p = 0; p < 6; p++) w6[p] = w_route[p][r];
#pragma unroll
        for (int ccx = 0; ccx < 32; ccx += 8) {
          int c = c0 + ccx;
          int chunk = (((c >> 3) ^ (r & 7)) << 4);
          char* a0 = featsB + ((0 * ROWS + r) << 9) + chunk;
          char* a1 = featsB + ((1 * ROWS + r) << 9) + chunk;
          char* a2 = featsB + ((2 * ROWS + r) << 9) + chunk;
          bf16x8 f0 = *(bf16x8*)a0, f1 = *(bf16x8*)a1, f2 = *(bf16x8*)a2;
          bf16x8 u0, u1, u2;
#pragma unroll
          for (int i = 0; i < 8; i++) {
            float a = (float)f0[i], b = (float)f1[i], d = (float)f2[i];
            u0[i] = (bf16)(a + w6[2] * b + w6[4] * d);
            u1[i] = (bf16)(b + w6[0] * a + w6[5] * d);
            u2[i] = (bf16)(d + w6[1] * a + w6[3] * b);
          }
          *(bf16x8*)a0 = u0; *(bf16x8*)a1 = u1; *(bf16x8*)a2 = u2;
        }
      }
      BARP();
    }
    for (int l = 0; l < 3; l++) {
      zacc6();
      gemm(ws + (PB_LPW1 + l * 8) * PSZ, 8, l, 0, 0);
      epi_bias_store(lpb1 + l * 256, l, true);
      zacc6();
      gemm(ws + (PB_LPW2 + l * 8) * PSZ, 8, l, 0, 0);
      ln_epi(lpb2 + l * 256, lng + l * 256, lnb + l * 256, l);
    }
  }

  zacc6();
  gemm(ws + PB_FAW1 * PSZ, 24, 0, 1, 2);
  epi_bias_store(fab1, 0, true);   // h4 -> feats[0] (feats dead)
  zacc6();
  gemm(ws + PB_FAW2 * PSZ, 8, 0, 0, 0);
  ln_epi(fab2, fng, fnb, -1);

  // w output (last iteration's gates): out[B*256 + p*B + row]
  if (t < 6 * ROWS) {
    int p = t / ROWS, r = t % ROWS;
    if (r0 + r < B_ROWS)
      out[(size_t)B_ROWS * 256 + (size_t)p * B_ROWS + r0 + r] = w_route[p][r];
  }
}

extern "C" void kernel_launch(void* const* d_in, const int* in_sizes, int n_in,
                              void* d_out, int out_size, void* d_ws, size_t ws_size,
                              hipStream_t stream) {
  const float* xf   = (const float*)d_in[0];
  const float* xm   = (const float*)d_in[1];
  const float* xc   = (const float*)d_in[2];
  const float* pW0  = (const float*)d_in[3];
  const float* pb0  = (const float*)d_in[4];
  const float* pW1  = (const float*)d_in[5];
  const float* pb1  = (const float*)d_in[6];
  const float* pW2  = (const float*)d_in[7];
  const float* pb2  = (const float*)d_in[8];
  const float* rW1  = (const float*)d_in[9];
  const float* rb1  = (const float*)d_in[10];
  const float* rW2  = (const float*)d_in[11];
  const float* rb2  = (const float*)d_in[12];
  const float* lpW1 = (const float*)d_in[13];
  const float* lpb1 = (const float*)d_in[14];
  const float* lpW2 = (const float*)d_in[15];
  const float* lpb2 = (const float*)d_in[16];
  const float* lng  = (const float*)d_in[17];
  const float* lnb  = (const float*)d_in[18];
  const float* faW1 = (const float*)d_in[19];
  const float* fab1 = (const float*)d_in[20];
  const float* faW2 = (const float*)d_in[21];
  const float* fab2 = (const float*)d_in[22];
  const float* fng  = (const float*)d_in[23];
  const float* fnb  = (const float*)d_in[24];
  (void)in_sizes; (void)n_in; (void)out_size; (void)ws_size;

  bf16* ws = (bf16*)d_ws;
  float* out = (float*)d_out;

  int nblk = (B_ROWS + ROWS - 1) / ROWS;  // 683
  wprep_kernel<<<204, 256, 0, stream>>>(pW0, pW1, pW2, rW1, lpW1, lpW2, faW1, faW2, ws);
  fused_kernel<<<nblk, 512, 0, stream>>>(xf, xm, xc, pb0, pb1, pb2, rb1, rW2, rb2,
                                         lpb1, lpb2, lng, lnb, fab1, fab2, fng, fnb,
                                         ws, out);
}